// Round 1
// baseline (1706.359 us; speedup 1.0000x reference)
//
#include <hip/hip_runtime.h>
#include <math.h>

#define H 64
#define HK 8
#define HD 64
#define DM 1024
#define WINDOW 128
#define GQA (H / HK)
#define Bv 2
#define Sv 1024

// ---------------------------------------------------------------------------
// GEMM: out[m,n] = sum_k A[m,k] * W[n,k] + bias[n]
// A row-major [M,K], W row-major [N,K] (i.e. out = A @ W^T + bias)
// 64x64 tile, BK=16, 256 threads, 4x4 microtile per thread.
// LDS pad +4 keeps rows 16B-aligned so inner reads can be ds_read_b128.
// ---------------------------------------------------------------------------
#define BM 64
#define BN 64
#define BK 16

__global__ __launch_bounds__(256) void gemm_bt(const float* __restrict__ A,
                                               const float* __restrict__ W,
                                               const float* __restrict__ bias,
                                               float* __restrict__ out,
                                               int M, int N, int K) {
    __shared__ float As[BK][BM + 4];
    __shared__ float Ws[BK][BN + 4];
    const int t = threadIdx.x;
    const int m0 = blockIdx.y * BM;
    const int n0 = blockIdx.x * BN;
    const int tx = t & 15;        // 0..15 -> output col group
    const int ty = t >> 4;        // 0..15 -> output row group
    const int lm = t >> 2;        // 0..63  staging row
    const int lk = (t & 3) * 4;   // 0,4,8,12 staging k offset

    float acc[4][4] = {};

    for (int k0 = 0; k0 < K; k0 += BK) {
        float4 a4 = *(const float4*)(A + (size_t)(m0 + lm) * K + k0 + lk);
        float4 w4 = *(const float4*)(W + (size_t)(n0 + lm) * K + k0 + lk);
        As[lk + 0][lm] = a4.x; As[lk + 1][lm] = a4.y;
        As[lk + 2][lm] = a4.z; As[lk + 3][lm] = a4.w;
        Ws[lk + 0][lm] = w4.x; Ws[lk + 1][lm] = w4.y;
        Ws[lk + 2][lm] = w4.z; Ws[lk + 3][lm] = w4.w;
        __syncthreads();
#pragma unroll
        for (int kk = 0; kk < BK; ++kk) {
            float4 a = *(const float4*)&As[kk][ty * 4];
            float4 b = *(const float4*)&Ws[kk][tx * 4];
            float av[4] = {a.x, a.y, a.z, a.w};
            float bv[4] = {b.x, b.y, b.z, b.w};
#pragma unroll
            for (int i = 0; i < 4; ++i)
#pragma unroll
                for (int j = 0; j < 4; ++j) acc[i][j] += av[i] * bv[j];
        }
        __syncthreads();
    }

    float4 bias4 = *(const float4*)(bias + n0 + tx * 4);
    float bb[4] = {bias4.x, bias4.y, bias4.z, bias4.w};
#pragma unroll
    for (int i = 0; i < 4; ++i) {
        int m = m0 + ty * 4 + i;
        float4 o4;
        o4.x = acc[i][0] + bb[0];
        o4.y = acc[i][1] + bb[1];
        o4.z = acc[i][2] + bb[2];
        o4.w = acc[i][3] + bb[3];
        *(float4*)(out + (size_t)m * N + n0 + tx * 4) = o4;
    }
}

// ---------------------------------------------------------------------------
// Attention: one wave per (b, h, q_pos). Lane = head-dim element.
// Sliding window of 128 keys, causal, online softmax with sink logit merged
// at the end. Output written in place over the q buffer (each wave owns its
// own 64 floats: read once at start, written once at end -> race-free).
// ---------------------------------------------------------------------------
__global__ __launch_bounds__(256) void attn_kernel(float* __restrict__ q,      // [B*S, H*HD] in/out
                                                   const float* __restrict__ k, // [B*S, HK*HD]
                                                   const float* __restrict__ v, // [B*S, HK*HD]
                                                   const float* __restrict__ sinks) {
    const int wave = (int)((blockIdx.x * blockDim.x + threadIdx.x) >> 6);
    const int lane = threadIdx.x & 63;
    const int qp = wave % Sv;
    const int h  = (wave / Sv) % H;
    const int b  = wave / (Sv * H);
    const int hk = h / GQA;
    const float scale = 0.125f;  // 1/sqrt(64)

    const size_t qoff = ((size_t)(b * Sv + qp)) * (H * HD) + h * HD + lane;
    const float qd = q[qoff] * scale;

    float m = -INFINITY, l = 0.f, o = 0.f;
    int j0 = qp - (WINDOW - 1);
    if (j0 < 0) j0 = 0;

    const float* krow = k + (size_t)(b * Sv) * (HK * HD) + hk * HD + lane;
    const float* vrow = v + (size_t)(b * Sv) * (HK * HD) + hk * HD + lane;

    for (int j = j0; j <= qp; ++j) {
        float kd = krow[(size_t)j * (HK * HD)];
        float s = qd * kd;
#pragma unroll
        for (int off = 32; off >= 1; off >>= 1) s += __shfl_xor(s, off, 64);
        float vd = vrow[(size_t)j * (HK * HD)];
        float mn = fmaxf(m, s);
        float alpha = __expf(m - mn);   // first iter: exp(-inf)=0
        float p = __expf(s - mn);
        l = l * alpha + p;
        o = o * alpha + p * vd;
        m = mn;
    }
    // merge the per-head sink logit (extra softmax column, prob dropped)
    float sk = sinks[h];
    float mn = fmaxf(m, sk);
    float alpha = __expf(m - mn);
    l = l * alpha + __expf(sk - mn);
    o = o * alpha;

    q[qoff] = o / l;
}

// ---------------------------------------------------------------------------
extern "C" void kernel_launch(void* const* d_in, const int* in_sizes, int n_in,
                              void* d_out, int out_size, void* d_ws, size_t ws_size,
                              hipStream_t stream) {
    const float* x     = (const float*)d_in[0];
    const float* Wq    = (const float*)d_in[1];
    const float* bq    = (const float*)d_in[2];
    const float* Wk    = (const float*)d_in[3];
    const float* bk    = (const float*)d_in[4];
    const float* Wv    = (const float*)d_in[5];
    const float* bv    = (const float*)d_in[6];
    const float* Wo    = (const float*)d_in[7];
    const float* bo    = (const float*)d_in[8];
    const float* sinks = (const float*)d_in[9];
    float* out = (float*)d_out;

    const int M = Bv * Sv;            // 2048 rows
    float* ws = (float*)d_ws;
    float* qbuf = ws;                               // [2048, 4096] (reused as attn out)
    float* kbuf = qbuf + (size_t)M * (H * HD);      // [2048, 512]
    float* vbuf = kbuf + (size_t)M * (HK * HD);     // [2048, 512]

    dim3 blk(256);
    // QKV projections
    gemm_bt<<<dim3((H * HD) / BN, M / BM), blk, 0, stream>>>(x, Wq, bq, qbuf, M, H * HD, DM);
    gemm_bt<<<dim3((HK * HD) / BN, M / BM), blk, 0, stream>>>(x, Wk, bk, kbuf, M, HK * HD, DM);
    gemm_bt<<<dim3((HK * HD) / BN, M / BM), blk, 0, stream>>>(x, Wv, bv, vbuf, M, HK * HD, DM);

    // Attention (in-place over qbuf)
    const int total_waves = Bv * H * Sv;                 // 131072
    attn_kernel<<<dim3(total_waves * 64 / 256), blk, 0, stream>>>(qbuf, kbuf, vbuf, sinks);

    // Output projection
    gemm_bt<<<dim3(DM / BN, M / BM), blk, 0, stream>>>(qbuf, Wo, bo, out, M, DM, H * HD);
}

// Round 2
// 865.971 us; speedup vs baseline: 1.9705x; 1.9705x over previous
//
#include <hip/hip_runtime.h>
#include <math.h>

#define H 64
#define HK 8
#define HD 64
#define DM 1024
#define WINDOW 128
#define GQA (H / HK)
#define Bv 2
#define Sv 1024

// ---------------------------------------------------------------------------
// GEMM: out[m,n] = sum_k A[m,k] * W[n,k] + bias[n]   (out = A @ W^T + bias)
// 64x64 tile, BK=16, 256 threads, 4x4 microtile per thread. (unchanged)
// ---------------------------------------------------------------------------
#define BM 64
#define BN 64
#define BK 16

__global__ __launch_bounds__(256) void gemm_bt(const float* __restrict__ A,
                                               const float* __restrict__ W,
                                               const float* __restrict__ bias,
                                               float* __restrict__ out,
                                               int M, int N, int K) {
    __shared__ float As[BK][BM + 4];
    __shared__ float Ws[BK][BN + 4];
    const int t = threadIdx.x;
    const int m0 = blockIdx.y * BM;
    const int n0 = blockIdx.x * BN;
    const int tx = t & 15;
    const int ty = t >> 4;
    const int lm = t >> 2;
    const int lk = (t & 3) * 4;

    float acc[4][4] = {};

    for (int k0 = 0; k0 < K; k0 += BK) {
        float4 a4 = *(const float4*)(A + (size_t)(m0 + lm) * K + k0 + lk);
        float4 w4 = *(const float4*)(W + (size_t)(n0 + lm) * K + k0 + lk);
        As[lk + 0][lm] = a4.x; As[lk + 1][lm] = a4.y;
        As[lk + 2][lm] = a4.z; As[lk + 3][lm] = a4.w;
        Ws[lk + 0][lm] = w4.x; Ws[lk + 1][lm] = w4.y;
        Ws[lk + 2][lm] = w4.z; Ws[lk + 3][lm] = w4.w;
        __syncthreads();
#pragma unroll
        for (int kk = 0; kk < BK; ++kk) {
            float4 a = *(const float4*)&As[kk][ty * 4];
            float4 b = *(const float4*)&Ws[kk][tx * 4];
            float av[4] = {a.x, a.y, a.z, a.w};
            float bv[4] = {b.x, b.y, b.z, b.w};
#pragma unroll
            for (int i = 0; i < 4; ++i)
#pragma unroll
                for (int j = 0; j < 4; ++j) acc[i][j] += av[i] * bv[j];
        }
        __syncthreads();
    }

    float4 bias4 = *(const float4*)(bias + n0 + tx * 4);
    float bb[4] = {bias4.x, bias4.y, bias4.z, bias4.w};
#pragma unroll
    for (int i = 0; i < 4; ++i) {
        int m = m0 + ty * 4 + i;
        float4 o4;
        o4.x = acc[i][0] + bb[0];
        o4.y = acc[i][1] + bb[1];
        o4.z = acc[i][2] + bb[2];
        o4.w = acc[i][3] + bb[3];
        *(float4*)(out + (size_t)m * N + n0 + tx * 4) = o4;
    }
}

// ---------------------------------------------------------------------------
// Attention v2: lane = query. One wave = one head x 64 consecutive queries.
// Lane holds its q-vector (64 VGPR) and O-accumulator (64 VGPR). Key loop
// walks the union window [max(0,q0-128), q0+63] in 16-key chunks; K/V row
// addresses are wave-uniform -> compiler emits scalar (s_load) broadcasts,
// dot/update are v_fmac with SGPR operand. No shuffles, no LDS.
// Online softmax amortized per chunk: one O-rescale per 16 keys.
// Masked keys: s=-inf; m seeded at -1e30 so exp never sees inf-inf (NaN).
// ---------------------------------------------------------------------------
#define QT 64
#define CH 16

__global__ __launch_bounds__(512) void attn2(float* __restrict__ qb,        // [B*S, H*HD] in/out
                                             const float* __restrict__ kb,  // [B*S, HK*HD]
                                             const float* __restrict__ vb,  // [B*S, HK*HD]
                                             const float* __restrict__ sinks) {
    const int lane = threadIdx.x & 63;
    const int w    = threadIdx.x >> 6;      // 0..7 -> GQA sub-head
    const int q0   = blockIdx.x * QT;
    const int hk   = blockIdx.y;
    const int b    = blockIdx.z;
    const int h    = hk * GQA + w;
    const int qp   = q0 + lane;

    const float* krow = kb + (size_t)(b * Sv) * (HK * HD) + hk * HD;
    const float* vrow = vb + (size_t)(b * Sv) * (HK * HD) + hk * HD;
    float* qrow = qb + ((size_t)(b * Sv + qp)) * (H * HD) + h * HD;

    float qr[HD];
#pragma unroll
    for (int d = 0; d < HD; d += 4) {
        float4 t = *(const float4*)(qrow + d);
        qr[d + 0] = t.x * 0.125f;   // fold 1/sqrt(64)
        qr[d + 1] = t.y * 0.125f;
        qr[d + 2] = t.z * 0.125f;
        qr[d + 3] = t.w * 0.125f;
    }
    float o[HD] = {};
    float m = -1e30f, l = 0.f;

    int c0 = q0 - WINDOW;
    if (c0 < 0) c0 = 0;             // q0 mult of 64 -> c0 16-aligned
    const int jhi = q0 + QT - 1;

    for (int c = c0; c <= jhi; c += CH) {
        float s[CH];
#pragma unroll
        for (int jj = 0; jj < CH; ++jj) {
            const int j = c + jj;
            const float* kr = krow + (size_t)j * (HK * HD);
            float a0 = 0.f, a1 = 0.f, a2 = 0.f, a3 = 0.f;
#pragma unroll
            for (int d = 0; d < HD; d += 4) {
                a0 += qr[d + 0] * kr[d + 0];
                a1 += qr[d + 1] * kr[d + 1];
                a2 += qr[d + 2] * kr[d + 2];
                a3 += qr[d + 3] * kr[d + 3];
            }
            const float sv = (a0 + a1) + (a2 + a3);
            const bool ok = (j <= qp) && (qp - j < WINDOW);
            s[jj] = ok ? sv : -INFINITY;
        }
        float cm = s[0];
#pragma unroll
        for (int jj = 1; jj < CH; ++jj) cm = fmaxf(cm, s[jj]);
        const float mn = fmaxf(m, cm);          // finite: >= -1e30
        const float alpha = __expf(m - mn);
        l *= alpha;
#pragma unroll
        for (int d = 0; d < HD; ++d) o[d] *= alpha;
        m = mn;
#pragma unroll
        for (int jj = 0; jj < CH; ++jj) {
            const int j = c + jj;
            const float p = __expf(s[jj] - mn); // exp(-inf)=0 for masked
            l += p;
            const float* vr = vrow + (size_t)j * (HK * HD);
#pragma unroll
            for (int d = 0; d < HD; ++d) o[d] += p * vr[d];
        }
    }

    // merge per-head sink logit (extra softmax column, prob dropped)
    const float sk = sinks[h];
    const float mn = fmaxf(m, sk);
    const float alpha = __expf(m - mn);
    l = l * alpha + __expf(sk - mn);
    const float inv = alpha / l;                // o*alpha/l in one mult

#pragma unroll
    for (int d = 0; d < HD; d += 4) {
        float4 t;
        t.x = o[d + 0] * inv;
        t.y = o[d + 1] * inv;
        t.z = o[d + 2] * inv;
        t.w = o[d + 3] * inv;
        *(float4*)(qrow + d) = t;
    }
}

// ---------------------------------------------------------------------------
extern "C" void kernel_launch(void* const* d_in, const int* in_sizes, int n_in,
                              void* d_out, int out_size, void* d_ws, size_t ws_size,
                              hipStream_t stream) {
    const float* x     = (const float*)d_in[0];
    const float* Wq    = (const float*)d_in[1];
    const float* bq    = (const float*)d_in[2];
    const float* Wk    = (const float*)d_in[3];
    const float* bk    = (const float*)d_in[4];
    const float* Wv    = (const float*)d_in[5];
    const float* bv    = (const float*)d_in[6];
    const float* Wo    = (const float*)d_in[7];
    const float* bo    = (const float*)d_in[8];
    const float* sinks = (const float*)d_in[9];
    float* out = (float*)d_out;

    const int M = Bv * Sv;                          // 2048 rows
    float* ws = (float*)d_ws;
    float* qbuf = ws;                               // [2048, 4096] (reused as attn out)
    float* kbuf = qbuf + (size_t)M * (H * HD);      // [2048, 512]
    float* vbuf = kbuf + (size_t)M * (HK * HD);     // [2048, 512]

    dim3 blk(256);
    gemm_bt<<<dim3((H * HD) / BN, M / BM), blk, 0, stream>>>(x, Wq, bq, qbuf, M, H * HD, DM);
    gemm_bt<<<dim3((HK * HD) / BN, M / BM), blk, 0, stream>>>(x, Wk, bk, kbuf, M, HK * HD, DM);
    gemm_bt<<<dim3((HK * HD) / BN, M / BM), blk, 0, stream>>>(x, Wv, bv, vbuf, M, HK * HD, DM);

    attn2<<<dim3(Sv / QT, HK, Bv), dim3(512), 0, stream>>>(qbuf, kbuf, vbuf, sinks);

    gemm_bt<<<dim3(DM / BN, M / BM), blk, 0, stream>>>(qbuf, Wo, bo, out, M, DM, H * HD);
}

// Round 3
// 395.357 us; speedup vs baseline: 4.3160x; 2.1903x over previous
//
#include <hip/hip_runtime.h>
#include <math.h>

#define H 64
#define HK 8
#define HD 64
#define DM 1024
#define WINDOW 128
#define GQA (H / HK)
#define Bv 2
#define Sv 1024

typedef _Float16 f16;
typedef __attribute__((ext_vector_type(8))) _Float16 f16x8;
typedef __attribute__((ext_vector_type(4))) _Float16 f16x4;
typedef __attribute__((ext_vector_type(4))) float f32x4;

// ---------------------------------------------------------------------------
// async global->LDS, 16B per lane. LDS dest is wave-uniform base + lane*16.
// ---------------------------------------------------------------------------
__device__ __forceinline__ void gload_lds16(const void* g, void* l) {
    __builtin_amdgcn_global_load_lds((const __attribute__((address_space(1))) void*)g,
                                     (__attribute__((address_space(3))) void*)l, 16, 0, 0);
}

// ---------------------------------------------------------------------------
// f16 MFMA GEMM body: out = A @ W^T + bias. A [M,K], W [N,K], both f16
// row-major (K contiguous). 128x128 tile, BK=64, 256 threads = 4 waves in
// 2x2, each wave 64x64 = 4x4 MFMA 16x16x32 tiles.
// Staging: global_load_lds 16B/lane; LDS chunk index XOR-swizzled with
// (row&7) so frag ds_read_b128 is 2-way on banks (free) instead of 16-way.
// ---------------------------------------------------------------------------
template <typename OutT>
__device__ __forceinline__ void gemm_body(const f16* __restrict__ A,
                                          const f16* __restrict__ W,
                                          const float* __restrict__ bias,
                                          OutT* __restrict__ out,
                                          int bx, int by, int M, int N, int K) {
    __shared__ __align__(16) f16 As[128 * 64];
    __shared__ __align__(16) f16 Bs[128 * 64];

    const int t    = threadIdx.x;
    const int lane = t & 63;
    const int w    = t >> 6;        // wave 0..3
    const int wm   = w >> 1;        // 2x2 wave grid
    const int wn   = w & 1;
    const int lr   = lane & 15;
    const int quad = lane >> 4;
    const int m0   = by * 128;
    const int n0   = bx * 128;

    const int srow = lane >> 3;             // 0..7  staging row within 8-row chunk
    const int gsw  = lane & 7;              // 0..7  staging chunk slot

    f32x4 acc[4][4] = {};

    for (int k0 = 0; k0 < K; k0 += 64) {
#pragma unroll
        for (int i = 0; i < 4; ++i) {
            const int row = (w * 4 + i) * 8 + srow;       // 0..127
            const int g   = gsw ^ (row & 7);              // swizzled global chunk
            gload_lds16(A + (size_t)(m0 + row) * K + k0 + g * 8, As + (w * 4 + i) * 512);
            gload_lds16(W + (size_t)(n0 + row) * K + k0 + g * 8, Bs + (w * 4 + i) * 512);
        }
        __syncthreads();
#pragma unroll
        for (int ks = 0; ks < 2; ++ks) {
            f16x8 af[4], bf[4];
#pragma unroll
            for (int tt = 0; tt < 4; ++tt) {
                const int m  = wm * 64 + tt * 16 + lr;
                const int ca = (ks * 4 + quad) ^ (m & 7);
                af[tt] = *(const f16x8*)(As + m * 64 + ca * 8);
                const int n  = wn * 64 + tt * 16 + lr;
                const int cb = (ks * 4 + quad) ^ (n & 7);
                bf[tt] = *(const f16x8*)(Bs + n * 64 + cb * 8);
            }
#pragma unroll
            for (int i = 0; i < 4; ++i)
#pragma unroll
                for (int j = 0; j < 4; ++j)
                    acc[i][j] = __builtin_amdgcn_mfma_f32_16x16x32_f16(af[i], bf[j], acc[i][j], 0, 0, 0);
        }
        __syncthreads();
    }

    // C/D layout: col = lane&15, row = quad*4 + reg
#pragma unroll
    for (int i = 0; i < 4; ++i) {
        const int grow = m0 + wm * 64 + i * 16 + quad * 4;
#pragma unroll
        for (int j = 0; j < 4; ++j) {
            const int gcol = n0 + wn * 64 + j * 16 + lr;
            const float bz = bias[gcol];
#pragma unroll
            for (int r = 0; r < 4; ++r)
                out[(size_t)(grow + r) * N + gcol] = (OutT)(acc[i][j][r] + bz);
        }
    }
}

template <typename OutT>
__global__ __launch_bounds__(256) void gemm_mfma(const f16* __restrict__ A,
                                                 const f16* __restrict__ W,
                                                 const float* __restrict__ bias,
                                                 OutT* __restrict__ out,
                                                 int M, int N, int K) {
    gemm_body<OutT>(A, W, bias, out, blockIdx.x, blockIdx.y, M, N, K);
}

// K and V projections fused into one launch (128 blocks instead of 2x64).
__global__ __launch_bounds__(256) void kv_gemm(const f16* __restrict__ xh,
                                               const f16* __restrict__ Wkh,
                                               const f16* __restrict__ Wvh,
                                               const float* __restrict__ bk,
                                               const float* __restrict__ bv,
                                               float* __restrict__ kbuf,
                                               float* __restrict__ vbuf) {
    const bool isv = blockIdx.x >= 4;
    gemm_body<float>(xh, isv ? Wvh : Wkh, isv ? bv : bk, isv ? vbuf : kbuf,
                     blockIdx.x & 3, blockIdx.y, Bv * Sv, HK * HD, DM);
}

// ---------------------------------------------------------------------------
// Fused fp32 -> f16 conversion of x, Wq, Wk, Wv, Wo into contiguous ws.
// One float4 per thread. Boundaries in float4 units (compile-time sizes).
// ---------------------------------------------------------------------------
#define C_X  524288     // 2048*1024/4
#define C_WQ 1572864    // + 4096*1024/4
#define C_WK 1703936    // + 512*1024/4
#define C_WV 1835008    // + 512*1024/4
#define C_WO 2883584    // + 1024*4096/4

__global__ __launch_bounds__(256) void convert_all(const float* __restrict__ x,
                                                   const float* __restrict__ Wq,
                                                   const float* __restrict__ Wk,
                                                   const float* __restrict__ Wv,
                                                   const float* __restrict__ Wo,
                                                   f16* __restrict__ dst) {
    const int i = blockIdx.x * 256 + threadIdx.x;   // float4 index
    const float* src;
    int off;
    if (i < C_X)       { src = x;  off = i; }
    else if (i < C_WQ) { src = Wq; off = i - C_X; }
    else if (i < C_WK) { src = Wk; off = i - C_WQ; }
    else if (i < C_WV) { src = Wv; off = i - C_WK; }
    else               { src = Wo; off = i - C_WV; }
    const float4 v = ((const float4*)src)[off];
    f16x4 o;
    o[0] = (f16)v.x; o[1] = (f16)v.y; o[2] = (f16)v.z; o[3] = (f16)v.w;
    *(f16x4*)(dst + (size_t)i * 4) = o;
}

// ---------------------------------------------------------------------------
// Attention: lane = query. One wave = one head x 64 consecutive queries.
// Q read from f16 (once per wave), K/V fp32 wave-uniform scalar broadcasts,
// output written f16 (feeds the Wo MFMA GEMM). Online softmax per 16-key
// chunk; sink logit merged at the end.
// ---------------------------------------------------------------------------
#define QT 64
#define CH 16

__global__ __launch_bounds__(512) void attn2(const f16* __restrict__ qh,    // [B*S, H*HD]
                                             const float* __restrict__ kb,  // [B*S, HK*HD]
                                             const float* __restrict__ vb,  // [B*S, HK*HD]
                                             const float* __restrict__ sinks,
                                             f16* __restrict__ oh) {        // [B*S, H*HD]
    const int lane = threadIdx.x & 63;
    const int w    = threadIdx.x >> 6;      // 0..7 -> GQA sub-head
    const int q0   = blockIdx.x * QT;
    const int hk   = blockIdx.y;
    const int b    = blockIdx.z;
    const int h    = hk * GQA + w;
    const int qp   = q0 + lane;

    const float* krow = kb + (size_t)(b * Sv) * (HK * HD) + hk * HD;
    const float* vrow = vb + (size_t)(b * Sv) * (HK * HD) + hk * HD;
    const size_t qoff = ((size_t)(b * Sv + qp)) * (H * HD) + h * HD;

    float qr[HD];
#pragma unroll
    for (int d = 0; d < HD; d += 8) {
        f16x8 t = *(const f16x8*)(qh + qoff + d);
#pragma unroll
        for (int j = 0; j < 8; ++j) qr[d + j] = (float)t[j] * 0.125f;  // fold 1/sqrt(64)
    }
    float o[HD] = {};
    float m = -1e30f, l = 0.f;

    int c0 = q0 - WINDOW;
    if (c0 < 0) c0 = 0;
    const int jhi = q0 + QT - 1;

    for (int c = c0; c <= jhi; c += CH) {
        float s[CH];
#pragma unroll
        for (int jj = 0; jj < CH; ++jj) {
            const int j = c + jj;
            const float* kr = krow + (size_t)j * (HK * HD);
            float a0 = 0.f, a1 = 0.f, a2 = 0.f, a3 = 0.f;
#pragma unroll
            for (int d = 0; d < HD; d += 4) {
                a0 += qr[d + 0] * kr[d + 0];
                a1 += qr[d + 1] * kr[d + 1];
                a2 += qr[d + 2] * kr[d + 2];
                a3 += qr[d + 3] * kr[d + 3];
            }
            const float sv = (a0 + a1) + (a2 + a3);
            const bool ok = (j <= qp) && (qp - j < WINDOW);
            s[jj] = ok ? sv : -INFINITY;
        }
        float cm = s[0];
#pragma unroll
        for (int jj = 1; jj < CH; ++jj) cm = fmaxf(cm, s[jj]);
        const float mn = fmaxf(m, cm);
        const float alpha = __expf(m - mn);
        l *= alpha;
#pragma unroll
        for (int d = 0; d < HD; ++d) o[d] *= alpha;
        m = mn;
#pragma unroll
        for (int jj = 0; jj < CH; ++jj) {
            const int j = c + jj;
            const float p = __expf(s[jj] - mn);
            l += p;
            const float* vr = vrow + (size_t)j * (HK * HD);
#pragma unroll
            for (int d = 0; d < HD; ++d) o[d] += p * vr[d];
        }
    }

    const float sk = sinks[h];
    const float mn = fmaxf(m, sk);
    const float alpha = __expf(m - mn);
    l = l * alpha + __expf(sk - mn);
    const float inv = alpha / l;

#pragma unroll
    for (int d = 0; d < HD; d += 8) {
        f16x8 t;
#pragma unroll
        for (int j = 0; j < 8; ++j) t[j] = (f16)(o[d + j] * inv);
        *(f16x8*)(oh + qoff + d) = t;
    }
}

// ---------------------------------------------------------------------------
extern "C" void kernel_launch(void* const* d_in, const int* in_sizes, int n_in,
                              void* d_out, int out_size, void* d_ws, size_t ws_size,
                              hipStream_t stream) {
    const float* x     = (const float*)d_in[0];
    const float* Wq    = (const float*)d_in[1];
    const float* bq    = (const float*)d_in[2];
    const float* Wk    = (const float*)d_in[3];
    const float* bk    = (const float*)d_in[4];
    const float* Wv    = (const float*)d_in[5];
    const float* bv    = (const float*)d_in[6];
    const float* Wo    = (const float*)d_in[7];
    const float* bo    = (const float*)d_in[8];
    const float* sinks = (const float*)d_in[9];
    float* out = (float*)d_out;

    const int M = Bv * Sv;                     // 2048 rows
    // workspace layout (62 MB total)
    f16* xh  = (f16*)d_ws;                     // 2,097,152  (4 MB)
    f16* Wqh = xh  + 2097152;                  // 4,194,304  (8 MB)
    f16* Wkh = Wqh + 4194304;                  //   524,288  (1 MB)
    f16* Wvh = Wkh + 524288;                   //   524,288  (1 MB)
    f16* Woh = Wvh + 524288;                   // 4,194,304  (8 MB)
    f16* qh  = Woh + 4194304;                  // 8,388,608 (16 MB)
    f16* oh  = qh  + 8388608;                  // 8,388,608 (16 MB)
    float* kbuf = (float*)(oh + 8388608);      // 1,048,576  (4 MB)
    float* vbuf = kbuf + 1048576;              // 1,048,576  (4 MB)

    convert_all<<<dim3(C_WO / 256), dim3(256), 0, stream>>>(x, Wq, Wk, Wv, Wo, xh);

    // Q projection: [2048,1024] @ [4096,1024]^T -> f16 qh
    gemm_mfma<f16><<<dim3(32, 16), dim3(256), 0, stream>>>(xh, Wqh, bq, qh, M, H * HD, DM);
    // K+V projections fused: -> fp32 kbuf/vbuf
    kv_gemm<<<dim3(8, 16), dim3(256), 0, stream>>>(xh, Wkh, Wvh, bk, bv, kbuf, vbuf);

    attn2<<<dim3(Sv / QT, HK, Bv), dim3(512), 0, stream>>>(qh, kbuf, vbuf, sinks, oh);

    // Output projection: [2048,4096] @ [1024,4096]^T -> fp32 out
    gemm_mfma<float><<<dim3(8, 16), dim3(256), 0, stream>>>(oh, Woh, bo, out, M, DM, H * HD);
}

// Round 4
// 241.041 us; speedup vs baseline: 7.0791x; 1.6402x over previous
//
#include <hip/hip_runtime.h>
#include <math.h>

#define H 64
#define HK 8
#define HD 64
#define DM 1024
#define WINDOW 128
#define GQA (H / HK)
#define Bv 2
#define Sv 1024

typedef _Float16 f16;
typedef __attribute__((ext_vector_type(8))) _Float16 f16x8;
typedef __attribute__((ext_vector_type(4))) _Float16 f16x4;
typedef __attribute__((ext_vector_type(4))) float f32x4;

// ---------------------------------------------------------------------------
// async global->LDS, 16B per lane. LDS dest is wave-uniform base + lane*16.
// ---------------------------------------------------------------------------
__device__ __forceinline__ void gload_lds16(const void* g, void* l) {
    __builtin_amdgcn_global_load_lds((const __attribute__((address_space(1))) void*)g,
                                     (__attribute__((address_space(3))) void*)l, 16, 0, 0);
}

// ---------------------------------------------------------------------------
// f16 MFMA GEMM body: out = A @ W^T + bias. A [M,K], W [N,K], both f16.
// 128x128 tile, BK=64, 256 threads = 4 waves 2x2, 4x4 MFMA 16x16x32 each.
// MODE 0: fp32 linear out. MODE 1: f16 linear out.
// MODE 2: f16 K-layout  khb[b][hk][s][d]   (b=m>>10, s=m&1023, hk=n>>6, d=n&63)
// MODE 3: f16 V^T-layout vtb[b][hk][d][s]
// ---------------------------------------------------------------------------
template <int MODE>
__device__ __forceinline__ void gemm_body(const f16* __restrict__ A,
                                          const f16* __restrict__ W,
                                          const float* __restrict__ bias,
                                          void* __restrict__ outp,
                                          int bx, int by, int M, int N, int K,
                                          f16* As, f16* Bs) {
    const int t    = threadIdx.x;
    const int lane = t & 63;
    const int w    = t >> 6;
    const int wm   = w >> 1;
    const int wn   = w & 1;
    const int lr   = lane & 15;
    const int quad = lane >> 4;
    const int m0   = by * 128;
    const int n0   = bx * 128;

    const int srow = lane >> 3;
    const int gsw  = lane & 7;

    f32x4 acc[4][4] = {};

    for (int k0 = 0; k0 < K; k0 += 64) {
#pragma unroll
        for (int i = 0; i < 4; ++i) {
            const int row = (w * 4 + i) * 8 + srow;
            const int g   = gsw ^ (row & 7);
            gload_lds16(A + (size_t)(m0 + row) * K + k0 + g * 8, As + (w * 4 + i) * 512);
            gload_lds16(W + (size_t)(n0 + row) * K + k0 + g * 8, Bs + (w * 4 + i) * 512);
        }
        __syncthreads();
#pragma unroll
        for (int ks = 0; ks < 2; ++ks) {
            f16x8 af[4], bf[4];
#pragma unroll
            for (int tt = 0; tt < 4; ++tt) {
                const int m  = wm * 64 + tt * 16 + lr;
                const int ca = (ks * 4 + quad) ^ (m & 7);
                af[tt] = *(const f16x8*)(As + m * 64 + ca * 8);
                const int n  = wn * 64 + tt * 16 + lr;
                const int cb = (ks * 4 + quad) ^ (n & 7);
                bf[tt] = *(const f16x8*)(Bs + n * 64 + cb * 8);
            }
#pragma unroll
            for (int i = 0; i < 4; ++i)
#pragma unroll
                for (int j = 0; j < 4; ++j)
                    acc[i][j] = __builtin_amdgcn_mfma_f32_16x16x32_f16(af[i], bf[j], acc[i][j], 0, 0, 0);
        }
        __syncthreads();
    }

    // C/D layout: col = lane&15, row = quad*4 + reg
#pragma unroll
    for (int i = 0; i < 4; ++i) {
        const int grow = m0 + wm * 64 + i * 16 + quad * 4;
#pragma unroll
        for (int j = 0; j < 4; ++j) {
            const int gcol = n0 + wn * 64 + j * 16 + lr;
            const float bz = bias[gcol];
            if (MODE == 0) {
#pragma unroll
                for (int r = 0; r < 4; ++r)
                    ((float*)outp)[(size_t)(grow + r) * N + gcol] = acc[i][j][r] + bz;
            } else if (MODE == 1) {
#pragma unroll
                for (int r = 0; r < 4; ++r)
                    ((f16*)outp)[(size_t)(grow + r) * N + gcol] = (f16)(acc[i][j][r] + bz);
            } else if (MODE == 2) {
                // khb[((b*8+hk)*1024+s)*64+d]
                const size_t base = (size_t)(grow >> 10) * 524288 + (size_t)(gcol >> 6) * 65536
                                  + (size_t)(grow & 1023) * 64 + (gcol & 63);
#pragma unroll
                for (int r = 0; r < 4; ++r)
                    ((f16*)outp)[base + (size_t)r * 64] = (f16)(acc[i][j][r] + bz);
            } else {
                // vtb[((b*8+hk)*64+d)*1024+s] : 4 consecutive s -> one 8B store
                const size_t base = ((size_t)(grow >> 10) * 512 + gcol) * 1024 + (grow & 1023);
                f16x4 o;
#pragma unroll
                for (int r = 0; r < 4; ++r) o[r] = (f16)(acc[i][j][r] + bz);
                *(f16x4*)((f16*)outp + base) = o;
            }
        }
    }
}

__global__ __launch_bounds__(256) void q_gemm(const f16* __restrict__ A,
                                              const f16* __restrict__ W,
                                              const float* __restrict__ bias,
                                              f16* __restrict__ out,
                                              int M, int N, int K) {
    __shared__ __align__(16) f16 As[128 * 64];
    __shared__ __align__(16) f16 Bs[128 * 64];
    gemm_body<1>(A, W, bias, out, blockIdx.x, blockIdx.y, M, N, K, As, Bs);
}

__global__ __launch_bounds__(256) void o_gemm(const f16* __restrict__ A,
                                              const f16* __restrict__ W,
                                              const float* __restrict__ bias,
                                              float* __restrict__ out,
                                              int M, int N, int K) {
    __shared__ __align__(16) f16 As[128 * 64];
    __shared__ __align__(16) f16 Bs[128 * 64];
    gemm_body<0>(A, W, bias, out, blockIdx.x, blockIdx.y, M, N, K, As, Bs);
}

__global__ __launch_bounds__(256) void kv_gemm(const f16* __restrict__ xh,
                                               const f16* __restrict__ Wkh,
                                               const f16* __restrict__ Wvh,
                                               const float* __restrict__ bk,
                                               const float* __restrict__ bv,
                                               f16* __restrict__ khb,
                                               f16* __restrict__ vtb) {
    __shared__ __align__(16) f16 As[128 * 64];
    __shared__ __align__(16) f16 Bs[128 * 64];
    if (blockIdx.x < 4)
        gemm_body<2>(xh, Wkh, bk, khb, blockIdx.x, blockIdx.y, Bv * Sv, HK * HD, DM, As, Bs);
    else
        gemm_body<3>(xh, Wvh, bv, vtb, blockIdx.x - 4, blockIdx.y, Bv * Sv, HK * HD, DM, As, Bs);
}

// ---------------------------------------------------------------------------
// Fused fp32 -> f16 conversion of x, Wq, Wk, Wv, Wo into contiguous ws.
// ---------------------------------------------------------------------------
#define C_X  524288     // 2048*1024/4
#define C_WQ 1572864    // + 4096*1024/4
#define C_WK 1703936    // + 512*1024/4
#define C_WV 1835008    // + 512*1024/4
#define C_WO 2883584    // + 1024*4096/4

__global__ __launch_bounds__(256) void convert_all(const float* __restrict__ x,
                                                   const float* __restrict__ Wq,
                                                   const float* __restrict__ Wk,
                                                   const float* __restrict__ Wv,
                                                   const float* __restrict__ Wo,
                                                   f16* __restrict__ dst) {
    const int i = blockIdx.x * 256 + threadIdx.x;
    const float* src;
    int off;
    if (i < C_X)       { src = x;  off = i; }
    else if (i < C_WQ) { src = Wq; off = i - C_X; }
    else if (i < C_WK) { src = Wk; off = i - C_WQ; }
    else if (i < C_WV) { src = Wv; off = i - C_WK; }
    else               { src = Wo; off = i - C_WV; }
    const float4 v = ((const float4*)src)[off];
    f16x4 o;
    o[0] = (f16)v.x; o[1] = (f16)v.y; o[2] = (f16)v.z; o[3] = (f16)v.w;
    *(f16x4*)(dst + (size_t)i * 4) = o;
}

// ---------------------------------------------------------------------------
// MFMA flash attention. Block = 256 thr = 4 waves = 4 GQA heads of one (b,hk).
// Window 128 -> 64-query tile needs exactly 192 keys -> single-pass softmax.
// LDS: K[192][64] f16 (stride 72), V^T[64][192] f16 (stride 200),
//      per-wave P[16][192] f16 (stride 200). 77 KB -> 2 blocks/CU.
// slot s in [0,192): key j = c0 + s, c0 = q0-128. allowed iff
// mq < s <= mq+128 and s >= smin (= -c0 clamp), mq = q - q0.
// ---------------------------------------------------------------------------
#define KT 192
#define KLS 72
#define VTS 200
#define PLS 200

__global__ __launch_bounds__(256) void attn_mfma(const f16* __restrict__ qh,   // [B*S][H*HD]
                                                 const f16* __restrict__ khb,  // [B][HK][S][HD]
                                                 const f16* __restrict__ vtb,  // [B][HK][HD][S]
                                                 const float* __restrict__ sinks,
                                                 f16* __restrict__ oh) {       // [B*S][H*HD]
    __shared__ __align__(16) f16 Kl[KT * KLS];
    __shared__ __align__(16) f16 Vt[HD * VTS];
    __shared__ __align__(16) f16 Pl[4 * 16 * PLS];

    const int t  = threadIdx.x;
    const int q0 = blockIdx.x * 64;
    const int hk = blockIdx.y >> 1;
    const int hh = blockIdx.y & 1;
    const int b  = blockIdx.z;
    const int c0 = q0 - WINDOW;

    const f16* kg = khb + (size_t)(b * HK + hk) * Sv * HD;   // [S][64]
    const f16* vg = vtb + (size_t)(b * HK + hk) * HD * Sv;   // [64][S]

    // stage K: 192 rows x 8 chunks of 8 f16
#pragma unroll
    for (int ii = 0; ii < 6; ++ii) {
        const int i = ii * 256 + t;
        const int slot = i >> 3, c = i & 7;
        const int j = c0 + slot;
        f16x8 val = {};
        if (j >= 0) val = *(const f16x8*)(kg + (size_t)j * HD + c * 8);
        *(f16x8*)(&Kl[slot * KLS + c * 8]) = val;
    }
    // stage V^T: 64 rows x 24 chunks of 8 f16
#pragma unroll
    for (int ii = 0; ii < 6; ++ii) {
        const int i = ii * 256 + t;
        const int d = i / 24, c = i % 24;
        const int j0 = c0 + c * 8;
        f16x8 val = {};
        if (j0 >= 0) val = *(const f16x8*)(vg + (size_t)d * Sv + j0);
        *(f16x8*)(&Vt[d * VTS + c * 8]) = val;
    }
    __syncthreads();

    const int lane = t & 63;
    const int w    = t >> 6;
    const int h    = hk * GQA + hh * 4 + w;
    const int lr   = lane & 15;
    const int quad = lane >> 4;
    f16* Pw = Pl + w * 16 * PLS;

    // Q fragments: A[m=lane&15][k=quad*8+j], 4 mtiles x 2 ksteps
    f16x8 qf[4][2];
#pragma unroll
    for (int mt = 0; mt < 4; ++mt) {
        const int q = q0 + mt * 16 + lr;
        const f16* qrow = qh + (size_t)(b * Sv + q) * (H * HD) + h * HD;
#pragma unroll
        for (int ks = 0; ks < 2; ++ks)
            qf[mt][ks] = *(const f16x8*)(qrow + ks * 32 + quad * 8);
    }
    const float sk   = sinks[h];
    const int   smin = (c0 < 0) ? -c0 : 0;
    const float scale = 0.125f;

#pragma unroll
    for (int mt = 0; mt < 4; ++mt) {
        // ---- S = Q @ K^T : [16 q][192 keys] ----
        f32x4 S[12];
#pragma unroll
        for (int nt = 0; nt < 12; ++nt) {
            f32x4 a = {};
#pragma unroll
            for (int ks = 0; ks < 2; ++ks) {
                f16x8 bf = *(const f16x8*)(&Kl[(nt * 16 + lr) * KLS + ks * 32 + quad * 8]);
                a = __builtin_amdgcn_mfma_f32_16x16x32_f16(qf[mt][ks], bf, a, 0, 0, 0);
            }
            S[nt] = a;
        }
        // ---- mask + scale + row max ----
        const int slot = lr;  // col base; actual slot = nt*16 + lr
        float rmax[4] = {-1e30f, -1e30f, -1e30f, -1e30f};
#pragma unroll
        for (int nt = 0; nt < 12; ++nt) {
            const int sl = nt * 16 + slot;
#pragma unroll
            for (int r = 0; r < 4; ++r) {
                const int mq = mt * 16 + quad * 4 + r;
                const bool ok = (sl > mq) && (sl <= mq + WINDOW) && (sl >= smin);
                const float v = ok ? S[nt][r] * scale : -INFINITY;
                S[nt][r] = v;
                rmax[r] = fmaxf(rmax[r], v);
            }
        }
#pragma unroll
        for (int off = 1; off < 16; off <<= 1)
#pragma unroll
            for (int r = 0; r < 4; ++r)
                rmax[r] = fmaxf(rmax[r], __shfl_xor(rmax[r], off, 64));
        float mrow[4], lsum[4];
#pragma unroll
        for (int r = 0; r < 4; ++r) { mrow[r] = fmaxf(rmax[r], sk); lsum[r] = 0.f; }
        // ---- exp + row sum, P -> LDS (C->A layout transform) ----
#pragma unroll
        for (int nt = 0; nt < 12; ++nt) {
#pragma unroll
            for (int r = 0; r < 4; ++r) {
                const float p = __expf(S[nt][r] - mrow[r]);  // exp(-inf)=0 for masked
                lsum[r] += p;
                Pw[(quad * 4 + r) * PLS + nt * 16 + lr] = (f16)p;
            }
        }
#pragma unroll
        for (int off = 1; off < 16; off <<= 1)
#pragma unroll
            for (int r = 0; r < 4; ++r)
                lsum[r] += __shfl_xor(lsum[r], off, 64);
        float inv[4];
#pragma unroll
        for (int r = 0; r < 4; ++r)
            inv[r] = 1.f / (lsum[r] + __expf(sk - mrow[r]));  // sink column
        // ---- O = P @ V : [16 q][64 d] ----
        f32x4 O[4] = {};
#pragma unroll
        for (int kc = 0; kc < 6; ++kc) {
            const f16x8 pa = *(const f16x8*)(&Pw[lr * PLS + kc * 32 + quad * 8]);
#pragma unroll
            for (int dt = 0; dt < 4; ++dt) {
                const f16x8 vf = *(const f16x8*)(&Vt[(dt * 16 + lr) * VTS + kc * 32 + quad * 8]);
                O[dt] = __builtin_amdgcn_mfma_f32_16x16x32_f16(pa, vf, O[dt], 0, 0, 0);
            }
        }
        // ---- epilogue: divide by l, store f16 ----
#pragma unroll
        for (int dt = 0; dt < 4; ++dt) {
#pragma unroll
            for (int r = 0; r < 4; ++r) {
                const int q = q0 + mt * 16 + quad * 4 + r;
                oh[(size_t)(b * Sv + q) * (H * HD) + h * HD + dt * 16 + lr] =
                    (f16)(O[dt][r] * inv[r]);
            }
        }
    }
}

// ---------------------------------------------------------------------------
extern "C" void kernel_launch(void* const* d_in, const int* in_sizes, int n_in,
                              void* d_out, int out_size, void* d_ws, size_t ws_size,
                              hipStream_t stream) {
    const float* x     = (const float*)d_in[0];
    const float* Wq    = (const float*)d_in[1];
    const float* bq    = (const float*)d_in[2];
    const float* Wk    = (const float*)d_in[3];
    const float* bk    = (const float*)d_in[4];
    const float* Wv    = (const float*)d_in[5];
    const float* bv    = (const float*)d_in[6];
    const float* Wo    = (const float*)d_in[7];
    const float* bo    = (const float*)d_in[8];
    const float* sinks = (const float*)d_in[9];
    float* out = (float*)d_out;

    const int M = Bv * Sv;                     // 2048 rows
    f16* xh  = (f16*)d_ws;                     // 2,097,152
    f16* Wqh = xh  + 2097152;                  // 4,194,304
    f16* Wkh = Wqh + 4194304;                  //   524,288
    f16* Wvh = Wkh + 524288;                   //   524,288
    f16* Woh = Wvh + 524288;                   // 4,194,304
    f16* qh  = Woh + 4194304;                  // 8,388,608
    f16* oh  = qh  + 8388608;                  // 8,388,608
    f16* khb = oh  + 8388608;                  // 1,048,576  [B][HK][S][HD]
    f16* vtb = khb + 1048576;                  // 1,048,576  [B][HK][HD][S]

    convert_all<<<dim3(C_WO / 256), dim3(256), 0, stream>>>(x, Wq, Wk, Wv, Wo, xh);

    q_gemm<<<dim3(32, 16), dim3(256), 0, stream>>>(xh, Wqh, bq, qh, M, H * HD, DM);
    kv_gemm<<<dim3(8, 16), dim3(256), 0, stream>>>(xh, Wkh, Wvh, bk, bv, khb, vtb);

    attn_mfma<<<dim3(Sv / 64, HK * 2, Bv), dim3(256), 0, stream>>>(qh, khb, vtb, sinks, oh);

    o_gemm<<<dim3(8, 16), dim3(256), 0, stream>>>(oh, Woh, bo, out, M, DM, H * HD);
}

// Round 5
// 204.008 us; speedup vs baseline: 8.3642x; 1.1815x over previous
//
#include <hip/hip_runtime.h>
#include <math.h>

#define H 64
#define HK 8
#define HD 64
#define DM 1024
#define WINDOW 128
#define GQA (H / HK)
#define Bv 2
#define Sv 1024

typedef _Float16 f16;
typedef __attribute__((ext_vector_type(8))) _Float16 f16x8;
typedef __attribute__((ext_vector_type(4))) _Float16 f16x4;
typedef __attribute__((ext_vector_type(4))) float f32x4;

// ---------------------------------------------------------------------------
// async global->LDS, 16B per lane. LDS dest is wave-uniform base + lane*16.
// ---------------------------------------------------------------------------
__device__ __forceinline__ void gload_lds16(const void* g, void* l) {
    __builtin_amdgcn_global_load_lds((const __attribute__((address_space(1))) void*)g,
                                     (__attribute__((address_space(3))) void*)l, 16, 0, 0);
}

// ---------------------------------------------------------------------------
// f16 MFMA GEMM body: out = A @ W^T (+ bias). A [M,*], W [N,*], lda = leading
// stride, K = loop bound (<= lda for split-K). 128x128 tile, BK=64,
// 256 thr = 4 waves 2x2, each 4x4 MFMA 16x16x32.
// MODE 1: f16 linear out (stride N)        [Q projection]
// MODE 2: f16 K-layout  khb[b][hk][s][d]   (lc = gcol&511)
// MODE 3: f16 V^T-layout vtb[b][hk][d][s]  (lc = gcol&511)
// MODE 4: fp32 linear partial, no bias     [split-K o-proj]
// ---------------------------------------------------------------------------
template <int MODE>
__device__ __forceinline__ void gemm_body(const f16* __restrict__ A,
                                          const f16* __restrict__ W,
                                          const float* __restrict__ bias,
                                          void* __restrict__ outp,
                                          int bx, int by, int N, int K, int lda,
                                          f16* As, f16* Bs) {
    const int t    = threadIdx.x;
    const int lane = t & 63;
    const int w    = t >> 6;
    const int wm   = w >> 1;
    const int wn   = w & 1;
    const int lr   = lane & 15;
    const int quad = lane >> 4;
    const int m0   = by * 128;
    const int n0   = bx * 128;

    const int srow = lane >> 3;
    const int gsw  = lane & 7;

    f32x4 acc[4][4] = {};

    for (int k0 = 0; k0 < K; k0 += 64) {
#pragma unroll
        for (int i = 0; i < 4; ++i) {
            const int row = (w * 4 + i) * 8 + srow;
            const int g   = gsw ^ (row & 7);
            gload_lds16(A + (size_t)(m0 + row) * lda + k0 + g * 8, As + (w * 4 + i) * 512);
            gload_lds16(W + (size_t)(n0 + row) * lda + k0 + g * 8, Bs + (w * 4 + i) * 512);
        }
        __syncthreads();
#pragma unroll
        for (int ks = 0; ks < 2; ++ks) {
            f16x8 af[4], bf[4];
#pragma unroll
            for (int tt = 0; tt < 4; ++tt) {
                const int m  = wm * 64 + tt * 16 + lr;
                const int ca = (ks * 4 + quad) ^ (m & 7);
                af[tt] = *(const f16x8*)(As + m * 64 + ca * 8);
                const int n  = wn * 64 + tt * 16 + lr;
                const int cb = (ks * 4 + quad) ^ (n & 7);
                bf[tt] = *(const f16x8*)(Bs + n * 64 + cb * 8);
            }
#pragma unroll
            for (int i = 0; i < 4; ++i)
#pragma unroll
                for (int j = 0; j < 4; ++j)
                    acc[i][j] = __builtin_amdgcn_mfma_f32_16x16x32_f16(af[i], bf[j], acc[i][j], 0, 0, 0);
        }
        __syncthreads();
    }

    // C/D layout: col = lane&15, row = quad*4 + reg
#pragma unroll
    for (int i = 0; i < 4; ++i) {
        const int grow = m0 + wm * 64 + i * 16 + quad * 4;
#pragma unroll
        for (int j = 0; j < 4; ++j) {
            const int gcol = n0 + wn * 64 + j * 16 + lr;
            if (MODE == 1) {
                const float bz = bias[gcol];
#pragma unroll
                for (int r = 0; r < 4; ++r)
                    ((f16*)outp)[(size_t)(grow + r) * N + gcol] = (f16)(acc[i][j][r] + bz);
            } else if (MODE == 2) {
                const float bz = bias[gcol];
                const int lc = gcol & 511;   // khb[((b*8+hk)*1024+s)*64+d]
                const size_t base = (size_t)(grow >> 10) * 524288 + (size_t)(lc >> 6) * 65536
                                  + (size_t)(grow & 1023) * 64 + (lc & 63);
#pragma unroll
                for (int r = 0; r < 4; ++r)
                    ((f16*)outp)[base + (size_t)r * 64] = (f16)(acc[i][j][r] + bz);
            } else if (MODE == 3) {
                const float bz = bias[gcol];
                const int lc = gcol & 511;   // vtb[((b*8+hk)*64+d)*1024+s]
                const size_t base = ((size_t)(grow >> 10) * 512 + lc) * 1024 + (grow & 1023);
                f16x4 o;
#pragma unroll
                for (int r = 0; r < 4; ++r) o[r] = (f16)(acc[i][j][r] + bz);
                *(f16x4*)((f16*)outp + base) = o;
            } else {  // MODE 4: fp32 partial, no bias
#pragma unroll
                for (int r = 0; r < 4; ++r)
                    ((float*)outp)[(size_t)(grow + r) * N + gcol] = acc[i][j][r];
            }
        }
    }
}

// Fused QKV projection: W = [Wq;Wk;Wv] as one [5120,1024] f16 matrix.
// bx<32 -> Q (f16 linear, N=4096), bx in [32,36) -> K layout, else V^T.
__global__ __launch_bounds__(256) void qkv_gemm(const f16* __restrict__ xh,
                                                const f16* __restrict__ Wf,
                                                const float* __restrict__ bf,
                                                f16* __restrict__ qh,
                                                f16* __restrict__ khb,
                                                f16* __restrict__ vtb) {
    __shared__ __align__(16) f16 As[128 * 64];
    __shared__ __align__(16) f16 Bs[128 * 64];
    const int bx = blockIdx.x, by = blockIdx.y;
    if (bx < 32)
        gemm_body<1>(xh, Wf, bf, qh, bx, by, H * HD, DM, DM, As, Bs);
    else if (bx < 36)
        gemm_body<2>(xh, Wf, bf, khb, bx, by, 0, DM, DM, As, Bs);
    else
        gemm_body<3>(xh, Wf, bf, vtb, bx, by, 0, DM, DM, As, Bs);
}

// Split-K output projection: K=4096 split 4 ways, fp32 partials.
__global__ __launch_bounds__(256) void o_gemm_split(const f16* __restrict__ oh,
                                                    const f16* __restrict__ Woh,
                                                    float* __restrict__ partials) {
    __shared__ __align__(16) f16 As[128 * 64];
    __shared__ __align__(16) f16 Bs[128 * 64];
    const int kz = blockIdx.z;
    gemm_body<4>(oh + kz * 1024, Woh + kz * 1024, nullptr,
                 partials + (size_t)kz * 2097152,
                 blockIdx.x, blockIdx.y, DM, 1024, H * HD, As, Bs);
}

// out = p0+p1+p2+p3 + bo  (float4 per thread)
__global__ __launch_bounds__(256) void reduce4(const float* __restrict__ partials,
                                               const float* __restrict__ bo,
                                               float* __restrict__ out) {
    const int i = blockIdx.x * 256 + threadIdx.x;        // float4 idx, [0, 524288)
    const float4* p = (const float4*)partials;
    float4 a = p[i];
    float4 b1 = p[i + 524288], b2 = p[i + 1048576], b3 = p[i + 1572864];
    float4 bz = ((const float4*)bo)[i & 255];            // 1024 cols = 256 float4
    float4 o;
    o.x = a.x + b1.x + b2.x + b3.x + bz.x;
    o.y = a.y + b1.y + b2.y + b3.y + bz.y;
    o.z = a.z + b1.z + b2.z + b3.z + bz.z;
    o.w = a.w + b1.w + b2.w + b3.w + bz.w;
    ((float4*)out)[i] = o;
}

// ---------------------------------------------------------------------------
// Fused fp32 -> f16 conversion: x -> xh, {Wq,Wk,Wv} -> wqkv (contig), Wo -> woh
// ---------------------------------------------------------------------------
#define C_X  524288     // 2048*1024/4
#define C_WQ 1572864    // + 4096*1024/4
#define C_WK 1703936    // + 512*1024/4
#define C_WV 1835008    // + 512*1024/4
#define C_WO 2883584    // + 1024*4096/4

__global__ __launch_bounds__(256) void convert_all(const float* __restrict__ x,
                                                   const float* __restrict__ Wq,
                                                   const float* __restrict__ Wk,
                                                   const float* __restrict__ Wv,
                                                   const float* __restrict__ Wo,
                                                   f16* __restrict__ xh,
                                                   f16* __restrict__ wqkv,
                                                   f16* __restrict__ woh) {
    const int i = blockIdx.x * 256 + threadIdx.x;
    const float* src;
    f16* dst;
    int off;
    if (i < C_X)       { src = x;  dst = xh;              off = i; }
    else if (i < C_WQ) { src = Wq; dst = wqkv;            off = i - C_X; }
    else if (i < C_WK) { src = Wk; dst = wqkv + 4194304;  off = i - C_WQ; }
    else if (i < C_WV) { src = Wv; dst = wqkv + 4718592;  off = i - C_WK; }
    else               { src = Wo; dst = woh;             off = i - C_WV; }
    const float4 v = ((const float4*)src)[off];
    f16x4 o;
    o[0] = (f16)v.x; o[1] = (f16)v.y; o[2] = (f16)v.z; o[3] = (f16)v.w;
    *(f16x4*)(dst + (size_t)off * 4) = o;
}

__global__ __launch_bounds__(256) void build_bias(const float* __restrict__ bq,
                                                  const float* __restrict__ bk,
                                                  const float* __restrict__ bv,
                                                  float* __restrict__ bf) {
    const int i = blockIdx.x * 256 + threadIdx.x;    // [0, 5120)
    float v;
    if (i < 4096)      v = bq[i];
    else if (i < 4608) v = bk[i - 4096];
    else               v = bv[i - 4608];
    bf[i] = v;
}

// ---------------------------------------------------------------------------
// MFMA flash attention (unchanged from R3). Block = 4 waves = 4 GQA heads of
// one (b,hk); 64-query tile x 192-key window, single-pass softmax + sink.
// ---------------------------------------------------------------------------
#define KT 192
#define KLS 72
#define VTS 200
#define PLS 200

__global__ __launch_bounds__(256) void attn_mfma(const f16* __restrict__ qh,
                                                 const f16* __restrict__ khb,
                                                 const f16* __restrict__ vtb,
                                                 const float* __restrict__ sinks,
                                                 f16* __restrict__ oh) {
    __shared__ __align__(16) f16 Kl[KT * KLS];
    __shared__ __align__(16) f16 Vt[HD * VTS];
    __shared__ __align__(16) f16 Pl[4 * 16 * PLS];

    const int t  = threadIdx.x;
    const int q0 = blockIdx.x * 64;
    const int hk = blockIdx.y >> 1;
    const int hh = blockIdx.y & 1;
    const int b  = blockIdx.z;
    const int c0 = q0 - WINDOW;

    const f16* kg = khb + (size_t)(b * HK + hk) * Sv * HD;
    const f16* vg = vtb + (size_t)(b * HK + hk) * HD * Sv;

#pragma unroll
    for (int ii = 0; ii < 6; ++ii) {
        const int i = ii * 256 + t;
        const int slot = i >> 3, c = i & 7;
        const int j = c0 + slot;
        f16x8 val = {};
        if (j >= 0) val = *(const f16x8*)(kg + (size_t)j * HD + c * 8);
        *(f16x8*)(&Kl[slot * KLS + c * 8]) = val;
    }
#pragma unroll
    for (int ii = 0; ii < 6; ++ii) {
        const int i = ii * 256 + t;
        const int d = i / 24, c = i % 24;
        const int j0 = c0 + c * 8;
        f16x8 val = {};
        if (j0 >= 0) val = *(const f16x8*)(vg + (size_t)d * Sv + j0);
        *(f16x8*)(&Vt[d * VTS + c * 8]) = val;
    }
    __syncthreads();

    const int lane = t & 63;
    const int w    = t >> 6;
    const int h    = hk * GQA + hh * 4 + w;
    const int lr   = lane & 15;
    const int quad = lane >> 4;
    f16* Pw = Pl + w * 16 * PLS;

    f16x8 qf[4][2];
#pragma unroll
    for (int mt = 0; mt < 4; ++mt) {
        const int q = q0 + mt * 16 + lr;
        const f16* qrow = qh + (size_t)(b * Sv + q) * (H * HD) + h * HD;
#pragma unroll
        for (int ks = 0; ks < 2; ++ks)
            qf[mt][ks] = *(const f16x8*)(qrow + ks * 32 + quad * 8);
    }
    const float sk   = sinks[h];
    const int   smin = (c0 < 0) ? -c0 : 0;
    const float scale = 0.125f;

#pragma unroll
    for (int mt = 0; mt < 4; ++mt) {
        f32x4 S[12];
#pragma unroll
        for (int nt = 0; nt < 12; ++nt) {
            f32x4 a = {};
#pragma unroll
            for (int ks = 0; ks < 2; ++ks) {
                f16x8 bfr = *(const f16x8*)(&Kl[(nt * 16 + lr) * KLS + ks * 32 + quad * 8]);
                a = __builtin_amdgcn_mfma_f32_16x16x32_f16(qf[mt][ks], bfr, a, 0, 0, 0);
            }
            S[nt] = a;
        }
        float rmax[4] = {-1e30f, -1e30f, -1e30f, -1e30f};
#pragma unroll
        for (int nt = 0; nt < 12; ++nt) {
            const int sl = nt * 16 + lr;
#pragma unroll
            for (int r = 0; r < 4; ++r) {
                const int mq = mt * 16 + quad * 4 + r;
                const bool ok = (sl > mq) && (sl <= mq + WINDOW) && (sl >= smin);
                const float v = ok ? S[nt][r] * scale : -INFINITY;
                S[nt][r] = v;
                rmax[r] = fmaxf(rmax[r], v);
            }
        }
#pragma unroll
        for (int off = 1; off < 16; off <<= 1)
#pragma unroll
            for (int r = 0; r < 4; ++r)
                rmax[r] = fmaxf(rmax[r], __shfl_xor(rmax[r], off, 64));
        float mrow[4], lsum[4];
#pragma unroll
        for (int r = 0; r < 4; ++r) { mrow[r] = fmaxf(rmax[r], sk); lsum[r] = 0.f; }
#pragma unroll
        for (int nt = 0; nt < 12; ++nt) {
#pragma unroll
            for (int r = 0; r < 4; ++r) {
                const float p = __expf(S[nt][r] - mrow[r]);
                lsum[r] += p;
                Pw[(quad * 4 + r) * PLS + nt * 16 + lr] = (f16)p;
            }
        }
#pragma unroll
        for (int off = 1; off < 16; off <<= 1)
#pragma unroll
            for (int r = 0; r < 4; ++r)
                lsum[r] += __shfl_xor(lsum[r], off, 64);
        float inv[4];
#pragma unroll
        for (int r = 0; r < 4; ++r)
            inv[r] = 1.f / (lsum[r] + __expf(sk - mrow[r]));
        f32x4 O[4] = {};
#pragma unroll
        for (int kc = 0; kc < 6; ++kc) {
            const f16x8 pa = *(const f16x8*)(&Pw[lr * PLS + kc * 32 + quad * 8]);
#pragma unroll
            for (int dt = 0; dt < 4; ++dt) {
                const f16x8 vf = *(const f16x8*)(&Vt[(dt * 16 + lr) * VTS + kc * 32 + quad * 8]);
                O[dt] = __builtin_amdgcn_mfma_f32_16x16x32_f16(pa, vf, O[dt], 0, 0, 0);
            }
        }
#pragma unroll
        for (int dt = 0; dt < 4; ++dt) {
#pragma unroll
            for (int r = 0; r < 4; ++r) {
                const int q = q0 + mt * 16 + quad * 4 + r;
                oh[(size_t)(b * Sv + q) * (H * HD) + h * HD + dt * 16 + lr] =
                    (f16)(O[dt][r] * inv[r]);
            }
        }
    }
}

// ---------------------------------------------------------------------------
extern "C" void kernel_launch(void* const* d_in, const int* in_sizes, int n_in,
                              void* d_out, int out_size, void* d_ws, size_t ws_size,
                              hipStream_t stream) {
    const float* x     = (const float*)d_in[0];
    const float* Wq    = (const float*)d_in[1];
    const float* bq    = (const float*)d_in[2];
    const float* Wk    = (const float*)d_in[3];
    const float* bk    = (const float*)d_in[4];
    const float* Wv    = (const float*)d_in[5];
    const float* bv    = (const float*)d_in[6];
    const float* Wo    = (const float*)d_in[7];
    const float* bo    = (const float*)d_in[8];
    const float* sinks = (const float*)d_in[9];
    float* out = (float*)d_out;

    // ws layout (f16 units). Dead-by-o_gemm prefix [xh..vtb] (34 MB) is
    // reused as the 32 MB split-K partial buffer.
    f16* xh   = (f16*)d_ws;                    // 2,097,152   [ 0, 4 MB)
    f16* wqkv = xh + 2097152;                  // 5,242,880   [ 4,14.5)
    f16* qh   = wqkv + 5242880;                // 8,388,608   [14.5,30.5)
    f16* khb  = qh + 8388608;                  // 1,048,576   [30.5,32.5)
    f16* vtb  = khb + 1048576;                 // 1,048,576   [32.5,34.5)
    f16* woh  = vtb + 1048576;                 // 4,194,304   [34.5,42.5)  LIVE at o_gemm
    f16* oh   = woh + 4194304;                 // 8,388,608   [42.5,58.5)  LIVE at o_gemm
    float* bqkv = (float*)(oh + 8388608);      // 5120 fp32
    float* partials = (float*)d_ws;            // 4 x 2M fp32 = 32 MB, aliases dead prefix

    convert_all<<<dim3(C_WO / 256), dim3(256), 0, stream>>>(x, Wq, Wk, Wv, Wo, xh, wqkv, woh);
    build_bias<<<dim3(20), dim3(256), 0, stream>>>(bq, bk, bv, bqkv);

    qkv_gemm<<<dim3(40, 16), dim3(256), 0, stream>>>(xh, wqkv, bqkv, qh, khb, vtb);

    attn_mfma<<<dim3(Sv / 64, HK * 2, Bv), dim3(256), 0, stream>>>(qh, khb, vtb, sinks, oh);

    o_gemm_split<<<dim3(8, 16, 4), dim3(256), 0, stream>>>(oh, woh, partials);
    reduce4<<<dim3(2048), dim3(256), 0, stream>>>(partials, bo, out);
}

// Round 7
// 182.643 us; speedup vs baseline: 9.3426x; 1.1170x over previous
//
#include <hip/hip_runtime.h>
#include <math.h>

#define H 64
#define HK 8
#define HD 64
#define DM 1024
#define WINDOW 128
#define GQA (H / HK)
#define Bv 2
#define Sv 1024

typedef _Float16 f16;
typedef __attribute__((ext_vector_type(8))) _Float16 f16x8;
typedef __attribute__((ext_vector_type(4))) _Float16 f16x4;
typedef __attribute__((ext_vector_type(4))) float f32x4;

__device__ __forceinline__ void gload_lds16(const void* g, void* l) {
    __builtin_amdgcn_global_load_lds((const __attribute__((address_space(1))) void*)g,
                                     (__attribute__((address_space(3))) void*)l, 16, 0, 0);
}

// ---------------------------------------------------------------------------
// QKV GEMM: 128x160 tile, BK=64, 256 thr = 4 waves (2x2, each 64x80 = 4x5
// MFMA 16x16x32). Grid 32x16 = 512 blocks = exactly 2/CU, single round.
// W = [Wq;Wk;Wv] fused [5120,1024] f16; epilogue routes per-16-col group:
//   cols [0,4096)    -> qh linear f16 (scaled by 1/8 for attention)
//   cols [4096,4608) -> khb[b][hk][s][d]
//   cols [4608,5120) -> vtb[b][hk][d][s]
// ---------------------------------------------------------------------------
__global__ __launch_bounds__(256, 2) void qkv_gemm(const f16* __restrict__ xh,
                                                   const f16* __restrict__ wqkv,
                                                   const float* __restrict__ bqkv,
                                                   f16* __restrict__ qh,
                                                   f16* __restrict__ khb,
                                                   f16* __restrict__ vtb) {
    __shared__ __align__(16) f16 As[128 * 64];
    __shared__ __align__(16) f16 Bs[160 * 64];

    const int t    = threadIdx.x;
    const int lane = t & 63;
    const int w    = t >> 6;
    const int lr   = lane & 15;
    const int quad = lane >> 4;
    const int srow = lane >> 3;
    const int gsw  = lane & 7;
    const int bx   = blockIdx.x & 31;
    const int by   = blockIdx.x >> 5;
    const int m0   = by * 128;
    const int n0   = bx * 160;
    const int wm   = w >> 1;
    const int wn   = w & 1;

    f32x4 acc[4][5] = {};

    for (int k0 = 0; k0 < DM; k0 += 64) {
#pragma unroll
        for (int i = 0; i < 4; ++i) {
            const int row = (w * 4 + i) * 8 + srow;
            const int g   = gsw ^ (row & 7);
            gload_lds16(xh + (size_t)(m0 + row) * DM + k0 + g * 8, As + (w * 4 + i) * 512);
        }
#pragma unroll
        for (int i = 0; i < 5; ++i) {
            const int row = (w * 5 + i) * 8 + srow;
            const int g   = gsw ^ (row & 7);
            gload_lds16(wqkv + (size_t)(n0 + row) * DM + k0 + g * 8, Bs + (w * 5 + i) * 512);
        }
        __syncthreads();
#pragma unroll
        for (int ks = 0; ks < 2; ++ks) {
            f16x8 af[4], bf[5];
#pragma unroll
            for (int tt = 0; tt < 4; ++tt) {
                const int m  = wm * 64 + tt * 16 + lr;
                const int ca = (ks * 4 + quad) ^ (m & 7);
                af[tt] = *(const f16x8*)(As + m * 64 + ca * 8);
            }
#pragma unroll
            for (int tt = 0; tt < 5; ++tt) {
                const int n  = wn * 80 + tt * 16 + lr;
                const int cb = (ks * 4 + quad) ^ (n & 7);
                bf[tt] = *(const f16x8*)(Bs + n * 64 + cb * 8);
            }
#pragma unroll
            for (int i = 0; i < 4; ++i)
#pragma unroll
                for (int j = 0; j < 5; ++j)
                    acc[i][j] = __builtin_amdgcn_mfma_f32_16x16x32_f16(af[i], bf[j], acc[i][j], 0, 0, 0);
        }
        __syncthreads();
    }

    // C/D layout: col = lane&15, row = quad*4 + reg. 16-col groups are
    // region-uniform (boundaries 4096/4608 are multiples of 16).
#pragma unroll
    for (int i = 0; i < 4; ++i) {
        const int grow = m0 + wm * 64 + i * 16 + quad * 4;
#pragma unroll
        for (int j = 0; j < 5; ++j) {
            const int gcb  = n0 + wn * 80 + j * 16;
            const int gcol = gcb + lr;
            const float bz = bqkv[gcol];
            if (gcb < 4096) {            // Q (pre-scaled by 1/8)
#pragma unroll
                for (int r = 0; r < 4; ++r)
                    qh[(size_t)(grow + r) * 4096 + gcol] = (f16)((acc[i][j][r] + bz) * 0.125f);
            } else if (gcb < 4608) {     // K: khb[((b*8+hk)*1024+s)*64+d]
                const int lc = gcol - 4096;
                const size_t base = (size_t)(grow >> 10) * 524288 + (size_t)(lc >> 6) * 65536
                                  + (size_t)(grow & 1023) * 64 + (lc & 63);
#pragma unroll
                for (int r = 0; r < 4; ++r)
                    khb[base + (size_t)r * 64] = (f16)(acc[i][j][r] + bz);
            } else {                     // V^T: vtb[((b*8+hk)*64+d)*1024+s]
                const int lc = gcol - 4608;
                const size_t base = ((size_t)(grow >> 10) * 512 + lc) * 1024 + (grow & 1023);
                f16x4 o;
#pragma unroll
                for (int r = 0; r < 4; ++r) o[r] = (f16)(acc[i][j][r] + bz);
                *(f16x4*)(vtb + base) = o;
            }
        }
    }
}

// ---------------------------------------------------------------------------
// O-projection split-K x4: 128x128 tile, fp32 partials (no bias).
// Grid 8x16x4 = 512 blocks.
// ---------------------------------------------------------------------------
__global__ __launch_bounds__(256, 2) void o_gemm_split(const f16* __restrict__ oh,
                                                       const f16* __restrict__ woh,
                                                       float* __restrict__ partials) {
    __shared__ __align__(16) f16 As[128 * 64];
    __shared__ __align__(16) f16 Bs[128 * 64];

    const int t    = threadIdx.x;
    const int lane = t & 63;
    const int w    = t >> 6;
    const int lr   = lane & 15;
    const int quad = lane >> 4;
    const int srow = lane >> 3;
    const int gsw  = lane & 7;
    const int kz   = blockIdx.z;
    const int m0   = blockIdx.y * 128;
    const int n0   = blockIdx.x * 128;
    const int wm   = w >> 1;
    const int wn   = w & 1;

    const f16* A = oh  + (size_t)kz * 1024;
    const f16* W = woh + (size_t)kz * 1024;
    float* P = partials + (size_t)kz * 2097152;

    f32x4 acc[4][4] = {};

    for (int k0 = 0; k0 < 1024; k0 += 64) {
#pragma unroll
        for (int i = 0; i < 4; ++i) {
            const int row = (w * 4 + i) * 8 + srow;
            const int g   = gsw ^ (row & 7);
            gload_lds16(A + (size_t)(m0 + row) * 4096 + k0 + g * 8, As + (w * 4 + i) * 512);
            gload_lds16(W + (size_t)(n0 + row) * 4096 + k0 + g * 8, Bs + (w * 4 + i) * 512);
        }
        __syncthreads();
#pragma unroll
        for (int ks = 0; ks < 2; ++ks) {
            f16x8 af[4], bf[4];
#pragma unroll
            for (int tt = 0; tt < 4; ++tt) {
                const int m  = wm * 64 + tt * 16 + lr;
                const int ca = (ks * 4 + quad) ^ (m & 7);
                af[tt] = *(const f16x8*)(As + m * 64 + ca * 8);
                const int n  = wn * 64 + tt * 16 + lr;
                const int cb = (ks * 4 + quad) ^ (n & 7);
                bf[tt] = *(const f16x8*)(Bs + n * 64 + cb * 8);
            }
#pragma unroll
            for (int i = 0; i < 4; ++i)
#pragma unroll
                for (int j = 0; j < 4; ++j)
                    acc[i][j] = __builtin_amdgcn_mfma_f32_16x16x32_f16(af[i], bf[j], acc[i][j], 0, 0, 0);
        }
        __syncthreads();
    }

#pragma unroll
    for (int i = 0; i < 4; ++i) {
        const int grow = m0 + wm * 64 + i * 16 + quad * 4;
#pragma unroll
        for (int j = 0; j < 4; ++j) {
            const int gcol = n0 + wn * 64 + j * 16 + lr;
#pragma unroll
            for (int r = 0; r < 4; ++r)
                P[(size_t)(grow + r) * 1024 + gcol] = acc[i][j][r];
        }
    }
}

// out = p0+p1+p2+p3 + bo  (float4 per thread)
__global__ __launch_bounds__(256) void reduce4(const float* __restrict__ partials,
                                               const float* __restrict__ bo,
                                               float* __restrict__ out) {
    const int i = blockIdx.x * 256 + threadIdx.x;
    const float4* p = (const float4*)partials;
    float4 a  = p[i];
    float4 b1 = p[i + 524288], b2 = p[i + 1048576], b3 = p[i + 1572864];
    float4 bz = ((const float4*)bo)[i & 255];
    float4 o;
    o.x = a.x + b1.x + b2.x + b3.x + bz.x;
    o.y = a.y + b1.y + b2.y + b3.y + bz.y;
    o.z = a.z + b1.z + b2.z + b3.z + bz.z;
    o.w = a.w + b1.w + b2.w + b3.w + bz.w;
    ((float4*)out)[i] = o;
}

// ---------------------------------------------------------------------------
// Fused fp32->f16 conversion + fused-bias build (first 5120 threads).
// ---------------------------------------------------------------------------
#define C_X  524288     // x:  2048*1024/4
#define C_WQ 1572864    // Wq: +4096*1024/4
#define C_WK 1703936    // Wk: +512*1024/4
#define C_WV 1835008    // Wv: +512*1024/4
#define C_WO 2883584    // Wo: +1024*4096/4

__global__ __launch_bounds__(256) void convert_all(const float* __restrict__ x,
                                                   const float* __restrict__ Wq,
                                                   const float* __restrict__ Wk,
                                                   const float* __restrict__ Wv,
                                                   const float* __restrict__ Wo,
                                                   const float* __restrict__ bq,
                                                   const float* __restrict__ bk,
                                                   const float* __restrict__ bv,
                                                   f16* __restrict__ xh,
                                                   f16* __restrict__ wqkv,
                                                   f16* __restrict__ woh,
                                                   float* __restrict__ bqkv) {
    const int i = blockIdx.x * 256 + threadIdx.x;
    if (i < 5120) {
        float v;
        if (i < 4096)      v = bq[i];
        else if (i < 4608) v = bk[i - 4096];
        else               v = bv[i - 4608];
        bqkv[i] = v;
    }
    const float* src;
    f16* dst;
    int off;
    if (i < C_X)       { src = x;  dst = xh;              off = i; }
    else if (i < C_WQ) { src = Wq; dst = wqkv;            off = i - C_X; }
    else if (i < C_WK) { src = Wk; dst = wqkv + 4194304;  off = i - C_WQ; }
    else if (i < C_WV) { src = Wv; dst = wqkv + 4718592;  off = i - C_WK; }
    else               { src = Wo; dst = woh;             off = i - C_WV; }
    const float4 v = ((const float4*)src)[off];
    f16x4 o;
    o[0] = (f16)v.x; o[1] = (f16)v.y; o[2] = (f16)v.z; o[3] = (f16)v.w;
    *(f16x4*)(dst + (size_t)off * 4) = o;
}

// ---------------------------------------------------------------------------
// MFMA flash attention (validated R3-R5 body; q pre-scaled in qkv epilogue).
// Block = 4 waves = 4 GQA heads of one (b,hk); 64q x 192k, single-pass
// softmax + sink.
// ---------------------------------------------------------------------------
#define KT 192
#define KLS 72
#define VTS 200
#define PLS 200

__global__ __launch_bounds__(256) void attn_mfma(const f16* __restrict__ qh,
                                                 const f16* __restrict__ khb,
                                                 const f16* __restrict__ vtb,
                                                 const float* __restrict__ sinks,
                                                 f16* __restrict__ oh) {
    __shared__ __align__(16) f16 Kl[KT * KLS];
    __shared__ __align__(16) f16 Vt[HD * VTS];
    __shared__ __align__(16) f16 Pl[4 * 16 * PLS];

    const int t  = threadIdx.x;
    const int q0 = blockIdx.x * 64;
    const int hk = blockIdx.y >> 1;
    const int hh = blockIdx.y & 1;
    const int b  = blockIdx.z;
    const int c0 = q0 - WINDOW;

    const f16* kg = khb + (size_t)(b * HK + hk) * Sv * HD;
    const f16* vg = vtb + (size_t)(b * HK + hk) * HD * Sv;

#pragma unroll
    for (int ii = 0; ii < 6; ++ii) {
        const int i = ii * 256 + t;
        const int slot = i >> 3, c = i & 7;
        const int j = c0 + slot;
        f16x8 val = {};
        if (j >= 0) val = *(const f16x8*)(kg + (size_t)j * HD + c * 8);
        *(f16x8*)(&Kl[slot * KLS + c * 8]) = val;
    }
#pragma unroll
    for (int ii = 0; ii < 6; ++ii) {
        const int i = ii * 256 + t;
        const int d = i / 24, c = i % 24;
        const int j0 = c0 + c * 8;
        f16x8 val = {};
        if (j0 >= 0) val = *(const f16x8*)(vg + (size_t)d * Sv + j0);
        *(f16x8*)(&Vt[d * VTS + c * 8]) = val;
    }
    __syncthreads();

    const int lane = t & 63;
    const int w    = t >> 6;
    const int h    = hk * GQA + hh * 4 + w;
    const int lr   = lane & 15;
    const int quad = lane >> 4;
    f16* Pw = Pl + w * 16 * PLS;

    f16x8 qf[4][2];
#pragma unroll
    for (int mt = 0; mt < 4; ++mt) {
        const int q = q0 + mt * 16 + lr;
        const f16* qrow = qh + (size_t)(b * Sv + q) * (H * HD) + h * HD;
#pragma unroll
        for (int ks = 0; ks < 2; ++ks)
            qf[mt][ks] = *(const f16x8*)(qrow + ks * 32 + quad * 8);
    }
    const float sk   = sinks[h];
    const int   smin = (c0 < 0) ? -c0 : 0;

#pragma unroll
    for (int mt = 0; mt < 4; ++mt) {
        f32x4 S[12];
#pragma unroll
        for (int nt = 0; nt < 12; ++nt) {
            f32x4 a = {};
#pragma unroll
            for (int ks = 0; ks < 2; ++ks) {
                f16x8 bfr = *(const f16x8*)(&Kl[(nt * 16 + lr) * KLS + ks * 32 + quad * 8]);
                a = __builtin_amdgcn_mfma_f32_16x16x32_f16(qf[mt][ks], bfr, a, 0, 0, 0);
            }
            S[nt] = a;
        }
        float rmax[4] = {-1e30f, -1e30f, -1e30f, -1e30f};
#pragma unroll
        for (int nt = 0; nt < 12; ++nt) {
            const int sl = nt * 16 + lr;
#pragma unroll
            for (int r = 0; r < 4; ++r) {
                const int mq = mt * 16 + quad * 4 + r;
                const bool ok = (sl > mq) && (sl <= mq + WINDOW) && (sl >= smin);
                const float v = ok ? S[nt][r] : -INFINITY;   // q pre-scaled
                S[nt][r] = v;
                rmax[r] = fmaxf(rmax[r], v);
            }
        }
#pragma unroll
        for (int off = 1; off < 16; off <<= 1)
#pragma unroll
            for (int r = 0; r < 4; ++r)
                rmax[r] = fmaxf(rmax[r], __shfl_xor(rmax[r], off, 64));
        float mrow[4], lsum[4];
#pragma unroll
        for (int r = 0; r < 4; ++r) { mrow[r] = fmaxf(rmax[r], sk); lsum[r] = 0.f; }
#pragma unroll
        for (int nt = 0; nt < 12; ++nt) {
#pragma unroll
            for (int r = 0; r < 4; ++r) {
                const float p = __expf(S[nt][r] - mrow[r]);
                lsum[r] += p;
                Pw[(quad * 4 + r) * PLS + nt * 16 + lr] = (f16)p;
            }
        }
#pragma unroll
        for (int off = 1; off < 16; off <<= 1)
#pragma unroll
            for (int r = 0; r < 4; ++r)
                lsum[r] += __shfl_xor(lsum[r], off, 64);
        float inv[4];
#pragma unroll
        for (int r = 0; r < 4; ++r)
            inv[r] = 1.f / (lsum[r] + __expf(sk - mrow[r]));
        f32x4 O[4] = {};
#pragma unroll
        for (int kc = 0; kc < 6; ++kc) {
            const f16x8 pa = *(const f16x8*)(&Pw[lr * PLS + kc * 32 + quad * 8]);
#pragma unroll
            for (int dt = 0; dt < 4; ++dt) {
                const f16x8 vf = *(const f16x8*)(&Vt[(dt * 16 + lr) * VTS + kc * 32 + quad * 8]);
                O[dt] = __builtin_amdgcn_mfma_f32_16x16x32_f16(pa, vf, O[dt], 0, 0, 0);
            }
        }
#pragma unroll
        for (int dt = 0; dt < 4; ++dt) {
#pragma unroll
            for (int r = 0; r < 4; ++r) {
                const int q = q0 + mt * 16 + quad * 4 + r;
                oh[(size_t)(b * Sv + q) * (H * HD) + h * HD + dt * 16 + lr] =
                    (f16)(O[dt][r] * inv[r]);
            }
        }
    }
}

// ---------------------------------------------------------------------------
extern "C" void kernel_launch(void* const* d_in, const int* in_sizes, int n_in,
                              void* d_out, int out_size, void* d_ws, size_t ws_size,
                              hipStream_t stream) {
    const float* x     = (const float*)d_in[0];
    const float* Wq    = (const float*)d_in[1];
    const float* bq    = (const float*)d_in[2];
    const float* Wk    = (const float*)d_in[3];
    const float* bk    = (const float*)d_in[4];
    const float* Wv    = (const float*)d_in[5];
    const float* bv    = (const float*)d_in[6];
    const float* Wo    = (const float*)d_in[7];
    const float* bo    = (const float*)d_in[8];
    const float* sinks = (const float*)d_in[9];
    float* out = (float*)d_out;

    // ws layout (f16 units). Dead-by-o_gemm prefix (xh/wqkv/qh/khb/vtb) is
    // aliased by the 32 MB split-K partial buffer.
    f16* xh   = (f16*)d_ws;                    // 2,097,152
    f16* wqkv = xh + 2097152;                  // 5,242,880
    f16* qh   = wqkv + 5242880;                // 8,388,608
    f16* khb  = qh + 8388608;                  // 1,048,576  [B][HK][S][HD]
    f16* vtb  = khb + 1048576;                 // 1,048,576  [B][HK][HD][S]
    f16* woh  = vtb + 1048576;                 // 4,194,304  LIVE at o_gemm
    f16* oh   = woh + 4194304;                 // 8,388,608  LIVE at o_gemm
    float* bqkv = (float*)(oh + 8388608);      // 5120 fp32
    float* partials = (float*)d_ws;            // 4 x 2M fp32 = 32 MB

    convert_all<<<dim3(C_WO / 256), dim3(256), 0, stream>>>(
        x, Wq, Wk, Wv, Wo, bq, bk, bv, xh, wqkv, woh, bqkv);

    qkv_gemm<<<dim3(512), dim3(256), 0, stream>>>(xh, wqkv, bqkv, qh, khb, vtb);

    attn_mfma<<<dim3(Sv / 64, HK * 2, Bv), dim3(256), 0, stream>>>(qh, khb, vtb, sinks, oh);

    o_gemm_split<<<dim3(8, 16, 4), dim3(256), 0, stream>>>(oh, woh, partials);
    reduce4<<<dim3(2048), dim3(256), 0, stream>>>(partials, bo, out);
}